// Round 5
// baseline (2242.164 us; speedup 1.0000x reference)
//
#include <hip/hip_runtime.h>
#include <stdint.h>

// Problem constants
#define HID 100
#define B_TOTAL 512
#define T_IN 1000
#define NB 2
#define BLOCK 256   // 4 waves, 1 wave/SIMD -> 512-reg budget per wave
#define RSTR 160    // f16 row stride (320 B): batch 1 lands 16 banks away

typedef __fp16 f16x8 __attribute__((ext_vector_type(8)));
typedef float f32x4 __attribute__((ext_vector_type(4)));

#define MF(A, B, C) __builtin_amdgcn_mfma_f32_16x16x32_f16((A), (B), (C), 0, 0, 0)
#define Z4 ((f32x4){0.f, 0.f, 0.f, 0.f})
#define ZH8 ((f16x8){(__fp16)0.f,(__fp16)0.f,(__fp16)0.f,(__fp16)0.f,(__fp16)0.f,(__fp16)0.f,(__fp16)0.f,(__fp16)0.f})

// ---- fast activation math (verified: absmax unchanged) ----
#if __has_builtin(__builtin_amdgcn_exp2f)
#define EXP2F(x) __builtin_amdgcn_exp2f(x)
#else
#define EXP2F(x) exp2f(x)
#endif
#if __has_builtin(__builtin_amdgcn_rcpf)
#define RCPF(x) __builtin_amdgcn_rcpf(x)
#else
#define RCPF(x) (1.0f / (x))
#endif
#define LOG2E 1.44269504f
__device__ __forceinline__ float sigm(float x) { return RCPF(1.0f + EXP2F(-LOG2E * x)); }
__device__ __forceinline__ float tanh_fast(float x) {
  return 1.0f - 2.0f * RCPF(EXP2F((2.0f * LOG2E) * x) + 1.0f);
}

// Gate-interleaved row permutation (R1/R2-verified): frag row m of N-tile tl holds
// original gate row g*100 + (4*tl + q), g = m&3, q = m>>2.
// => D: lane holds gates (i,f,g,o) of k=4*tl+(lane>>4), batch lane&1 in regs 0..3.
__device__ __forceinline__ int jmap(int tl, int m) { return (m & 3) * 100 + 4 * tl + (m >> 2); }

// weight element fetchers over padded K layouts (0 in pad regions).
// Bias fused at K=101 (hi) / 102 (lo) against B=1.0 — f32-exact via hi/lo f16 pair.
// L1 K-layout: [0..99]=h1, [100]=x, [101]=b_hi, [102]=b_lo, [103..127]=0
__device__ __forceinline__ __fp16 w1e(const float* Whh1, const float* Wih1,
                                      const float* bih1, const float* bhh1, int j, int k) {
  if (k < 100) return (__fp16)Whh1[j * 100 + k];
  if (k == 100) return (__fp16)Wih1[j];
  if (k == 101 || k == 102) {
    float b = bih1[j] + bhh1[j];
    __fp16 hi = (__fp16)b;
    return (k == 101) ? hi : (__fp16)(b - (float)hi);
  }
  return (__fp16)0.0f;
}
// L2 K-layout: [0..99]=h1(t), [100]=0(x-slot junk), [101]=b_hi, [102]=b_lo,
//              [103..111]=0, [112..211]=h2(t-1), [212..223]=0
__device__ __forceinline__ __fp16 w2e(const float* Wih2, const float* Whh2,
                                      const float* bih2, const float* bhh2, int j, int k) {
  if (k < 100) return (__fp16)Wih2[j * 100 + k];
  if (k == 101 || k == 102) {
    float b = bih2[j] + bhh2[j];
    __fp16 hi = (__fp16)b;
    return (k == 101) ? hi : (__fp16)(b - (float)hi);
  }
  if (k >= 112 && k < 212) return (__fp16)Whh2[j * 100 + (k - 112)];
  return (__fp16)0.0f;
}

// A-operand fragment builders: lane row m=lane&15, K elems (lane>>4)*8+0..7 of K-tile kt
__device__ __forceinline__ f16x8 mka1(const float* Whh1, const float* Wih1,
                                      const float* bih1, const float* bhh1,
                                      int tl, int kt, int m, int kg) {
  int j = jmap(tl, m);
  f16x8 r;
#pragma unroll
  for (int e = 0; e < 8; e++) r[e] = w1e(Whh1, Wih1, bih1, bhh1, j, kt * 32 + kg * 8 + e);
  return r;
}
__device__ __forceinline__ f16x8 mka2(const float* Wih2, const float* Whh2,
                                      const float* bih2, const float* bhh2,
                                      int tl, int kt, int m, int kg) {
  int j = jmap(tl, m);
  f16x8 r;
#pragma unroll
  for (int e = 0; e < 8; e++) r[e] = w2e(Wih2, Whh2, bih2, bhh2, j, kt * 32 + kg * 8 + e);
  return r;
}

__global__ __launch_bounds__(BLOCK, 1) void lstm2_mfma(
    const float* __restrict__ input,  // [512,1000]
    const float* __restrict__ Wih1,   // [400,1]
    const float* __restrict__ Whh1,   // [400,100]
    const float* __restrict__ bih1,
    const float* __restrict__ bhh1,
    const float* __restrict__ Wih2,   // [400,100]
    const float* __restrict__ Whh2,   // [400,100]
    const float* __restrict__ bih2,
    const float* __restrict__ bhh2,
    const float* __restrict__ Wlin,   // [1,100]
    const float* __restrict__ blin,   // [1]
    const int* __restrict__ futp,
    float* __restrict__ out)          // [512, 1000+future]
{
  // parity double-buffered activation vectors (B-operand sources)
  __shared__ __align__(16) __fp16 H1X[2][NB][RSTR];   // h1 | x@100 | 1.0@101,102 | 0
  __shared__ __align__(16) __fp16 H2s[2][NB][RSTR];   // h2 | 0 pads
  __shared__ __align__(16) float  xrow[NB][T_IN];     // staged inputs (8 KB)
  __shared__ __align__(16) float  partials[2][NB][4]; // [parity][batch][wave] Wlin.h2 partials

  const int tid = threadIdx.x;
  const int lane = tid & 63;
  const int wv = tid >> 6;          // 0..3
  const int b0 = blockIdx.x * NB;
  const int F = futp[0];
  const int TT = T_IN + F;

  // ---------------- init: stage + zero ----------------
  for (int i = tid; i < NB * T_IN; i += BLOCK) {
    int b = i / T_IN, tt = i % T_IN;
    xrow[b][tt] = input[(size_t)(b0 + b) * T_IN + tt];
  }
  for (int i = tid; i < 320; i += BLOCK) {   // 2*2*160 f16 = 320 u32 each
    ((uint32_t*)H1X)[i] = 0u;
    ((uint32_t*)H2s)[i] = 0u;
  }
  if (tid < 16) ((float*)partials)[tid] = 0.0f;

  const int n15 = lane & 15;
  const int kg = lane >> 4;         // K-chunk index 0..3
  const int bcol = lane & 1;        // batch for B-reads

  // ---- act geometry: lane activates ONE of its 7 accumulator quads ----
  const int sel = lane & 15;
  const int cg  = sel >> 1;                       // tile slot 0..7 (0..5 all waves, 6 wave3)
  const int ab  = sel & 1;                        // batch
  const int aq  = lane >> 4;                      // q 0..3
  const bool actv = (cg < 6) || (wv == 3 && cg == 6);
  const int ak = actv ? ((cg == 6) ? (96 + aq) : (16 * cg + 4 * wv + aq)) : 0;  // 0..99
  float c1v = 0.0f, c2v = 0.0f;                   // per-lane cell states
  const float blin0 = blin[0];
  const float wlsv = Wlin[ak];                    // safe: ak in [0,100)
  f32x4 wih1q;
#pragma unroll
  for (int g = 0; g < 4; g++) wih1q[g] = Wih1[g * 100 + ak];

  // ---- register-resident weight fragments: tiles {4j+wv, j=0..5} + tile24 (wave3) ----
  f16x8 W1f[7][4], W2f[7][7];
#pragma unroll
  for (int j = 0; j < 6; j++) {
    const int tl_ = 4 * j + wv;
#pragma unroll
    for (int kt = 0; kt < 4; kt++) W1f[j][kt] = mka1(Whh1, Wih1, bih1, bhh1, tl_, kt, n15, kg);
#pragma unroll
    for (int kt = 0; kt < 7; kt++) W2f[j][kt] = mka2(Wih2, Whh2, bih2, bhh2, tl_, kt, n15, kg);
  }
  if (wv == 3) {
#pragma unroll
    for (int kt = 0; kt < 4; kt++) W1f[6][kt] = mka1(Whh1, Wih1, bih1, bhh1, 24, kt, n15, kg);
#pragma unroll
    for (int kt = 0; kt < 7; kt++) W2f[6][kt] = mka2(Wih2, Whh2, bih2, bhh2, 24, kt, n15, kg);
  } else {
#pragma unroll
    for (int kt = 0; kt < 4; kt++) W1f[6][kt] = ZH8;
#pragma unroll
    for (int kt = 0; kt < 7; kt++) W2f[6][kt] = ZH8;
  }

  __syncthreads();
  // specials: bias-ones at K=101,102 (both parities/batches); x(0) into parity 1
  if (tid < 4) { H1X[tid >> 1][tid & 1][101] = (__fp16)1.0f; H1X[tid >> 1][tid & 1][102] = (__fp16)1.0f; }
  if (tid >= 4 && tid < 6) H1X[1][tid - 4][100] = (__fp16)xrow[tid - 4][0];
  __syncthreads();

  f16x8 bH1a[4], bH2[3], bl2m;
  f32x4 dA[7], cA[7];

// ---- B-operand reads (L1 and L2 share H1X kts 0..3) ----
#define RD_H1A(P) { _Pragma("unroll") for (int kt_ = 0; kt_ < 4; kt_++) \
    bH1a[kt_] = *(const f16x8*)&H1X[P][bcol][kt_ * 32 + kg * 8]; }
#define RD_L2M(P) { f16x8 hm_ = *(const f16x8*)&H2s[P][bcol][(kg >= 2) ? ((kg - 2) * 8) : 0]; \
    bl2m = (kg >= 2) ? hm_ : bH1a[3]; }
#define RD_H2P(P) { _Pragma("unroll") for (int kt_ = 0; kt_ < 3; kt_++) \
    bH2[kt_] = *(const f16x8*)&H2s[P][bcol][16 + kt_ * 32 + kg * 8]; }

// ---- MFMA bursts (bias arrives via K=101/102) ----
#define MFMA_L2 { _Pragma("unroll") for (int j = 0; j < 7; j++) { f32x4 a_ = Z4; \
    a_ = MF(W2f[j][0], bH1a[0], a_); a_ = MF(W2f[j][1], bH1a[1], a_); a_ = MF(W2f[j][2], bH1a[2], a_); \
    a_ = MF(W2f[j][3], bl2m, a_); \
    a_ = MF(W2f[j][4], bH2[0], a_); a_ = MF(W2f[j][5], bH2[1], a_); a_ = MF(W2f[j][6], bH2[2], a_); \
    dA[j] = a_; } }

#define MFMA_L1 { _Pragma("unroll") for (int j = 0; j < 7; j++) { f32x4 a_ = Z4; \
    a_ = MF(W1f[j][0], bH1a[0], a_); a_ = MF(W1f[j][1], bH1a[1], a_); \
    a_ = MF(W1f[j][2], bH1a[2], a_); a_ = MF(W1f[j][3], bH1a[3], a_); \
    cA[j] = a_; } }

#define SELD (cg==0?dA[0]:cg==1?dA[1]:cg==2?dA[2]:cg==3?dA[3]:cg==4?dA[4]:cg==5?dA[5]:dA[6])
#define SELC (cg==0?cA[0]:cg==1?cA[1]:cg==2?cA[2]:cg==3?cA[3]:cg==4?cA[4]:cg==5?cA[5]:cA[6])

// ---- in-register activations + per-wave Wlin.h2 partial (5 shfl_xor) ----
#define ACT2(W_, PW_) { f32x4 qq = SELD; \
    float sf_ = sigm(qq[1]), si_ = sigm(qq[0]), tg_ = tanh_fast(qq[2]); \
    c2v = sf_ * c2v + si_ * tg_; \
    float h_ = sigm(qq[3]) * tanh_fast(c2v); \
    if (actv) H2s[W_][ab][ak] = (__fp16)h_; \
    float pc_ = actv ? h_ * wlsv : 0.0f; \
    pc_ += __shfl_xor(pc_, 2, 64);  pc_ += __shfl_xor(pc_, 4, 64); \
    pc_ += __shfl_xor(pc_, 8, 64);  pc_ += __shfl_xor(pc_, 16, 64); \
    pc_ += __shfl_xor(pc_, 32, 64); \
    if (lane < 2) partials[PW_][lane][wv] = pc_; }

#define ACT1_TF(W_) { f32x4 qq = SELC; \
    float sf_ = sigm(qq[1]), si_ = sigm(qq[0]), tg_ = tanh_fast(qq[2]); \
    c1v = sf_ * c1v + si_ * tg_; \
    float h_ = sigm(qq[3]) * tanh_fast(c1v); \
    if (actv) H1X[W_][ab][ak] = (__fp16)h_; }

#define ACT1_AR(W_, YV_) { f32x4 qq = SELC; \
    qq[0] = fmaf(wih1q[0], (YV_), qq[0]); qq[1] = fmaf(wih1q[1], (YV_), qq[1]); \
    qq[2] = fmaf(wih1q[2], (YV_), qq[2]); qq[3] = fmaf(wih1q[3], (YV_), qq[3]); \
    float sf_ = sigm(qq[1]), si_ = sigm(qq[0]), tg_ = tanh_fast(qq[2]); \
    c1v = sf_ * c1v + si_ * tg_; \
    float h_ = sigm(qq[3]) * tanh_fast(c1v); \
    if (actv) H1X[W_][ab][ak] = (__fp16)h_; }

// y(t) = sum of 4 wave-partials + blin (per-lane batch = ab)
#define YSUM(PP_, DST_) { const f32x4 pv_ = *(const f32x4*)&partials[PP_][ab][0]; \
    DST_ = pv_[0] + pv_[1] + pv_[2] + pv_[3] + blin0; }

  // ---------------- prologue: L1 gates(0) from parity 1 (zeros + x(0)) ----------------
  RD_H1A(1)
  MFMA_L1
  ACT1_TF(0)                                           // h1(0) -> H1X[0]
  if (tid >= 80 && tid < 82) H1X[0][tid - 80][100] = (__fp16)xrow[tid - 80][1];  // x(1)
  __syncthreads();

  // ====== teacher-forced fused: iter t does L2(t) + L1(t+1); ONE barrier/step ======
  for (int t = 0; t < T_IN - 1; t++) {
    const int p = t & 1, w = p ^ 1;
    RD_H1A(p) RD_L2M(p) RD_H2P(p)
    MFMA_L2
    ACT2(w, p)                                         // h2(t) + partials(t)
    MFMA_L1
    if (wv == 0 && lane < 2 && t > 0) {                // store y(t-1), off critical path
      float yv_;
      YSUM(p ^ 1, yv_)
      out[(size_t)(b0 + lane) * TT + (t - 1)] = yv_;
    }
    if (tid >= 80 && tid < 82 && t + 2 < T_IN)
      H1X[w][tid - 80][100] = (__fp16)xrow[tid - 80][t + 2];  // x(t+2)
    ACT1_TF(w)                                         // h1(t+1)
    __syncthreads();
  }

  // ---- one-time AR patch: remove x-coefficient from L1 kt3 (x-slot is stale in AR) ----
  if (kg == 0) {
#pragma unroll
    for (int j = 0; j < 7; j++) W1f[j][3][4] = (__fp16)0.f;
  }

  // ====== autoregressive: 2 barriers/step; y via per-wave partial reduce ======
  for (int t = T_IN - 1; t < TT; t++) {
    const int p = t & 1, w = p ^ 1;
    RD_H1A(p) RD_L2M(p) RD_H2P(p)
    MFMA_L2                                            // gates2(t)
    if (t == T_IN - 1 && wv == 0 && lane < 2) {        // catch-up y(T_IN-2)
      float yv_;
      YSUM(p ^ 1, yv_)
      out[(size_t)(b0 + lane) * TT + (t - 1)] = yv_;
    }
    ACT2(w, p)                                         // h2(t) + partials(t)
    MFMA_L1                                            // L1(t+1) recurrent part (h1(t) only)
    __syncthreads();                                   // B1: h2(t) + partials visible
    float yv;
    YSUM(p, yv)                                        // y(t) = x(t+1), all lanes
    if (wv == 0 && lane < 2) out[(size_t)(b0 + lane) * TT + t] = yv;
    ACT1_AR(w, yv)                                     // h1(t+1), x-term added in-register
    __syncthreads();                                   // B2: h1(t+1) visible
  }
}

extern "C" void kernel_launch(void* const* d_in, const int* in_sizes, int n_in,
                              void* d_out, int out_size, void* d_ws, size_t ws_size,
                              hipStream_t stream) {
  const float* input = (const float*)d_in[0];
  const float* Wih1  = (const float*)d_in[1];
  const float* Whh1  = (const float*)d_in[2];
  const float* bih1  = (const float*)d_in[3];
  const float* bhh1  = (const float*)d_in[4];
  const float* Wih2  = (const float*)d_in[5];
  const float* Whh2  = (const float*)d_in[6];
  const float* bih2  = (const float*)d_in[7];
  const float* bhh2  = (const float*)d_in[8];
  const float* Wlin  = (const float*)d_in[9];
  const float* blin  = (const float*)d_in[10];
  const int*   futp  = (const int*)d_in[11];
  float* out = (float*)d_out;

  dim3 grid(B_TOTAL / NB);  // 256 blocks, 1 per CU
  dim3 block(BLOCK);
  hipLaunchKernelGGL(lstm2_mfma, grid, block, 0, stream,
                     input, Wih1, Whh1, bih1, bhh1, Wih2, Whh2, bih2, bhh2,
                     Wlin, blin, futp, out);
}

// Round 6
// 1888.988 us; speedup vs baseline: 1.1870x; 1.1870x over previous
//
#include <hip/hip_runtime.h>
#include <stdint.h>

// Problem constants
#define HID 100
#define B_TOTAL 512
#define T_IN 1000
#define NB 2
#define BLOCK 768   // 12 waves, 3 waves/SIMD -> 170-reg budget, 50% more TLP than R4
#define RSTR 160    // f16 row stride (320 B): batch 1 lands 16 banks away

typedef __fp16 f16x8 __attribute__((ext_vector_type(8)));
typedef float f32x4 __attribute__((ext_vector_type(4)));

#define MF(A, B, C) __builtin_amdgcn_mfma_f32_16x16x32_f16((A), (B), (C), 0, 0, 0)
#define Z4 ((f32x4){0.f, 0.f, 0.f, 0.f})

// ---- fast activation math (verified: absmax unchanged) ----
#if __has_builtin(__builtin_amdgcn_exp2f)
#define EXP2F(x) __builtin_amdgcn_exp2f(x)
#else
#define EXP2F(x) exp2f(x)
#endif
#if __has_builtin(__builtin_amdgcn_rcpf)
#define RCPF(x) __builtin_amdgcn_rcpf(x)
#else
#define RCPF(x) (1.0f / (x))
#endif
#define LOG2E 1.44269504f
__device__ __forceinline__ float sigm(float x) { return RCPF(1.0f + EXP2F(-LOG2E * x)); }
__device__ __forceinline__ float tanh_fast(float x) {
  return 1.0f - 2.0f * RCPF(EXP2F((2.0f * LOG2E) * x) + 1.0f);
}

// Gate-interleaved row permutation (R1/R2-verified): frag row m of N-tile tl holds
// original gate row g*100 + (4*tl + q), g = m&3, q = m>>2.
// => D: lane holds gates (i,f,g,o) of k=4*tl+(lane>>4), batch lane&1 in regs 0..3.
__device__ __forceinline__ int jmap(int tl, int m) { return (m & 3) * 100 + 4 * tl + (m >> 2); }

// weight element fetchers over padded K layouts (0 in pad regions).
// Bias fused at K=101 (hi) / 102 (lo) against B=1.0 — f32-exact via hi/lo f16 pair.
// L1 K-layout: [0..99]=h1, [100]=x, [101]=b_hi, [102]=b_lo, [103..127]=0
__device__ __forceinline__ __fp16 w1e(const float* Whh1, const float* Wih1,
                                      const float* bih1, const float* bhh1, int j, int k) {
  if (k < 100) return (__fp16)Whh1[j * 100 + k];
  if (k == 100) return (__fp16)Wih1[j];
  if (k == 101 || k == 102) {
    float b = bih1[j] + bhh1[j];
    __fp16 hi = (__fp16)b;
    return (k == 101) ? hi : (__fp16)(b - (float)hi);
  }
  return (__fp16)0.0f;
}
// L2 K-layout: [0..99]=h1(t), [100]=0(x-slot junk), [101]=b_hi, [102]=b_lo,
//              [103..111]=0, [112..211]=h2(t-1), [212..223]=0
__device__ __forceinline__ __fp16 w2e(const float* Wih2, const float* Whh2,
                                      const float* bih2, const float* bhh2, int j, int k) {
  if (k < 100) return (__fp16)Wih2[j * 100 + k];
  if (k == 101 || k == 102) {
    float b = bih2[j] + bhh2[j];
    __fp16 hi = (__fp16)b;
    return (k == 101) ? hi : (__fp16)(b - (float)hi);
  }
  if (k >= 112 && k < 212) return (__fp16)Whh2[j * 100 + (k - 112)];
  return (__fp16)0.0f;
}

// A-operand fragment builders: lane row m=lane&15, K elems (lane>>4)*8+0..7 of K-tile kt
__device__ __forceinline__ f16x8 mka1(const float* Whh1, const float* Wih1,
                                      const float* bih1, const float* bhh1,
                                      int tl, int kt, int m, int kg) {
  int j = jmap(tl, m);
  f16x8 r;
#pragma unroll
  for (int e = 0; e < 8; e++) r[e] = w1e(Whh1, Wih1, bih1, bhh1, j, kt * 32 + kg * 8 + e);
  return r;
}
__device__ __forceinline__ f16x8 mka2(const float* Wih2, const float* Whh2,
                                      const float* bih2, const float* bhh2,
                                      int tl, int kt, int m, int kg) {
  int j = jmap(tl, m);
  f16x8 r;
#pragma unroll
  for (int e = 0; e < 8; e++) r[e] = w2e(Wih2, Whh2, bih2, bhh2, j, kt * 32 + kg * 8 + e);
  return r;
}

__global__ __launch_bounds__(BLOCK, 3) void lstm2_mfma(
    const float* __restrict__ input,  // [512,1000]
    const float* __restrict__ Wih1,   // [400,1]
    const float* __restrict__ Whh1,   // [400,100]
    const float* __restrict__ bih1,
    const float* __restrict__ bhh1,
    const float* __restrict__ Wih2,   // [400,100]
    const float* __restrict__ Whh2,   // [400,100]
    const float* __restrict__ bih2,
    const float* __restrict__ bhh2,
    const float* __restrict__ Wlin,   // [1,100]
    const float* __restrict__ blin,   // [1]
    const int* __restrict__ futp,
    float* __restrict__ out)          // [512, 1000+future]
{
  // parity double-buffered activation vectors (B-operand sources)
  __shared__ __align__(16) __fp16 H1X[2][NB][RSTR];   // h1 | x@100 | 1.0@101,102 | 0
  __shared__ __align__(16) __fp16 H2s[2][NB][RSTR];   // h2 | 0 pads
  __shared__ __align__(16) float  xrow[NB][T_IN];     // staged inputs (8 KB)
  __shared__ __align__(16) __fp16 T24[11 * 64 * 8];   // tile-24 frags: 0..3=W1 kt0..3, 4..10=W2 kt0..6
  __shared__ __align__(16) float  partials[2][NB][12];// [parity][batch][wave] Wlin.h2 partials

  const int tid = threadIdx.x;
  const int lane = tid & 63;
  const int wv = tid >> 6;          // 0..11
  const int b0 = blockIdx.x * NB;
  const int F = futp[0];
  const int TT = T_IN + F;

  // ---------------- init: stage + zero ----------------
  for (int i = tid; i < NB * T_IN; i += BLOCK) {
    int b = i / T_IN, tt = i % T_IN;
    xrow[b][tt] = input[(size_t)(b0 + b) * T_IN + tt];
  }
  if (tid < 320) { ((uint32_t*)H1X)[tid] = 0u; ((uint32_t*)H2s)[tid] = 0u; }
  if (tid < 48) ((float*)partials)[tid] = 0.0f;

  const int n15 = lane & 15;
  const int kg = lane >> 4;         // K-chunk index 0..3
  const int bcol = lane & 1;        // batch for B-reads

  // ---- act geometry: lane activates one quad; tile24 split: L1->wave10, L2->wave11 ----
  const int sel = lane & 15;
  const int cg  = sel >> 1;                       // 0,1 = own tiles; 2 = tile24 (wv 10/11)
  const int ab  = sel & 1;                        // batch
  const int aq  = lane >> 4;                      // q 0..3
  const bool awr1 = (cg < 2) || (wv == 10 && cg == 2);
  const bool awr2 = (cg < 2) || (wv == 11 && cg == 2);
  const int ak = (cg == 0) ? (4 * wv + aq)
               : (cg == 1) ? (48 + 4 * wv + aq)
               : ((cg == 2 && wv >= 10) ? (96 + aq) : 0);   // 0..99
  float c1v = 0.0f, c2v = 0.0f;                   // per-lane cell states
  const float blin0 = blin[0];
  const float wlsv = Wlin[ak];
  f32x4 wih1q;
#pragma unroll
  for (int g = 0; g < 4; g++) wih1q[g] = Wih1[g * 100 + ak];

  // ---- register-resident weight fragments: tiles {wv, 12+wv} ----
  f16x8 W1f[2][4], W2f[2][7];
#pragma unroll
  for (int j = 0; j < 2; j++) {
    const int tl_ = wv + 12 * j;
#pragma unroll
    for (int kt = 0; kt < 4; kt++) W1f[j][kt] = mka1(Whh1, Wih1, bih1, bhh1, tl_, kt, n15, kg);
#pragma unroll
    for (int kt = 0; kt < 7; kt++) W2f[j][kt] = mka2(Wih2, Whh2, bih2, bhh2, tl_, kt, n15, kg);
  }
  // tile-24 fragments -> LDS
  if (tid < 64) {
    f16x8* TV = (f16x8*)T24;
    const int m_ = tid & 15, kg_ = tid >> 4;
#pragma unroll
    for (int kt = 0; kt < 4; kt++) TV[kt * 64 + tid] = mka1(Whh1, Wih1, bih1, bhh1, 24, kt, m_, kg_);
#pragma unroll
    for (int kt = 0; kt < 7; kt++) TV[(4 + kt) * 64 + tid] = mka2(Wih2, Whh2, bih2, bhh2, 24, kt, m_, kg_);
  }

  __syncthreads();
  // specials: bias-ones at K=101,102 (both parities/batches); x(0) into parity 1
  if (tid < 4) { H1X[tid >> 1][tid & 1][101] = (__fp16)1.0f; H1X[tid >> 1][tid & 1][102] = (__fp16)1.0f; }
  if (tid >= 4 && tid < 6) H1X[1][tid - 4][100] = (__fp16)xrow[tid - 4][0];
  __syncthreads();

  f16x8 bH1a[4], bH2[3], bl2m;
  f32x4 dA0, dA1, d24, cA0, cA1, c24;
  d24 = Z4; c24 = Z4;   // stay zero on waves without tile-24 duty

// ---- B-operand reads (L1 and L2 share H1X kts 0..3) ----
#define RD_H1A(P) { _Pragma("unroll") for (int kt_ = 0; kt_ < 4; kt_++) \
    bH1a[kt_] = *(const f16x8*)&H1X[P][bcol][kt_ * 32 + kg * 8]; }
#define RD_L2M(P) { f16x8 hm_ = *(const f16x8*)&H2s[P][bcol][(kg >= 2) ? ((kg - 2) * 8) : 0]; \
    bl2m = (kg >= 2) ? hm_ : bH1a[3]; }
#define RD_H2P(P) { _Pragma("unroll") for (int kt_ = 0; kt_ < 3; kt_++) \
    bH2[kt_] = *(const f16x8*)&H2s[P][bcol][16 + kt_ * 32 + kg * 8]; }

// ---- MFMA bursts (bias arrives via K=101/102) ----
#define MFMA_L2 { \
    dA0 = Z4; dA1 = Z4; \
    dA0 = MF(W2f[0][0], bH1a[0], dA0); dA1 = MF(W2f[1][0], bH1a[0], dA1); \
    dA0 = MF(W2f[0][1], bH1a[1], dA0); dA1 = MF(W2f[1][1], bH1a[1], dA1); \
    dA0 = MF(W2f[0][2], bH1a[2], dA0); dA1 = MF(W2f[1][2], bH1a[2], dA1); \
    dA0 = MF(W2f[0][3], bl2m,    dA0); dA1 = MF(W2f[1][3], bl2m,    dA1); \
    dA0 = MF(W2f[0][4], bH2[0],  dA0); dA1 = MF(W2f[1][4], bH2[0],  dA1); \
    dA0 = MF(W2f[0][5], bH2[1],  dA0); dA1 = MF(W2f[1][5], bH2[1],  dA1); \
    dA0 = MF(W2f[0][6], bH2[2],  dA0); dA1 = MF(W2f[1][6], bH2[2],  dA1); \
    if (wv == 11) { const f16x8* TV = (const f16x8*)T24; \
      d24 = Z4; \
      d24 = MF(TV[4 * 64 + lane], bH1a[0], d24); d24 = MF(TV[5 * 64 + lane], bH1a[1], d24); \
      d24 = MF(TV[6 * 64 + lane], bH1a[2], d24); d24 = MF(TV[7 * 64 + lane], bl2m, d24); \
      d24 = MF(TV[8 * 64 + lane], bH2[0], d24);  d24 = MF(TV[9 * 64 + lane], bH2[1], d24); \
      d24 = MF(TV[10 * 64 + lane], bH2[2], d24); } }

#define MFMA_L1 { \
    cA0 = Z4; cA1 = Z4; \
    cA0 = MF(W1f[0][0], bH1a[0], cA0); cA1 = MF(W1f[1][0], bH1a[0], cA1); \
    cA0 = MF(W1f[0][1], bH1a[1], cA0); cA1 = MF(W1f[1][1], bH1a[1], cA1); \
    cA0 = MF(W1f[0][2], bH1a[2], cA0); cA1 = MF(W1f[1][2], bH1a[2], cA1); \
    cA0 = MF(W1f[0][3], bH1a[3], cA0); cA1 = MF(W1f[1][3], bH1a[3], cA1); \
    if (wv == 10) { const f16x8* TV = (const f16x8*)T24; \
      c24 = Z4; \
      c24 = MF(TV[0 * 64 + lane], bH1a[0], c24); c24 = MF(TV[1 * 64 + lane], bH1a[1], c24); \
      c24 = MF(TV[2 * 64 + lane], bH1a[2], c24); c24 = MF(TV[3 * 64 + lane], bH1a[3], c24); } }

#define SELD_ ((cg == 0) ? dA0 : (cg == 1) ? dA1 : d24)
#define SELC_ ((cg == 0) ? cA0 : (cg == 1) ? cA1 : c24)

// ---- in-register activations + per-wave Wlin.h2 partial (5 shfl_xor) ----
#define ACT2(W_, PW_) { f32x4 qq = SELD_; \
    float sf_ = sigm(qq[1]), si_ = sigm(qq[0]), tg_ = tanh_fast(qq[2]); \
    c2v = sf_ * c2v + si_ * tg_; \
    float h_ = sigm(qq[3]) * tanh_fast(c2v); \
    if (awr2) H2s[W_][ab][ak] = (__fp16)h_; \
    float pc_ = awr2 ? h_ * wlsv : 0.0f; \
    pc_ += __shfl_xor(pc_, 2, 64);  pc_ += __shfl_xor(pc_, 4, 64); \
    pc_ += __shfl_xor(pc_, 8, 64);  pc_ += __shfl_xor(pc_, 16, 64); \
    pc_ += __shfl_xor(pc_, 32, 64); \
    if (lane < 2) partials[PW_][lane][wv] = pc_; }

#define ACT1_TF(W_) { f32x4 qq = SELC_; \
    float sf_ = sigm(qq[1]), si_ = sigm(qq[0]), tg_ = tanh_fast(qq[2]); \
    c1v = sf_ * c1v + si_ * tg_; \
    float h_ = sigm(qq[3]) * tanh_fast(c1v); \
    if (awr1) H1X[W_][ab][ak] = (__fp16)h_; }

#define ACT1_AR(W_, YV_) { f32x4 qq = SELC_; \
    qq[0] = fmaf(wih1q[0], (YV_), qq[0]); qq[1] = fmaf(wih1q[1], (YV_), qq[1]); \
    qq[2] = fmaf(wih1q[2], (YV_), qq[2]); qq[3] = fmaf(wih1q[3], (YV_), qq[3]); \
    float sf_ = sigm(qq[1]), si_ = sigm(qq[0]), tg_ = tanh_fast(qq[2]); \
    c1v = sf_ * c1v + si_ * tg_; \
    float h_ = sigm(qq[3]) * tanh_fast(c1v); \
    if (awr1) H1X[W_][ab][ak] = (__fp16)h_; }

// y = sum of 12 wave-partials + blin (per-lane batch = ab)
#define YSUM(PP_, DST_) { const f32x4* pp_ = (const f32x4*)&partials[PP_][ab][0]; \
    f32x4 s4_ = pp_[0] + pp_[1] + pp_[2]; \
    DST_ = (s4_[0] + s4_[1]) + (s4_[2] + s4_[3]) + blin0; }

  // ---------------- prologue: L1 gates(0) from parity 1 (zeros + x(0)) ----------------
  RD_H1A(1)
  MFMA_L1
  ACT1_TF(0)                                           // h1(0) -> H1X[0]
  if (tid >= 80 && tid < 82) H1X[0][tid - 80][100] = (__fp16)xrow[tid - 80][1];  // x(1)
  __syncthreads();

  // ====== teacher-forced fused: iter t does L2(t) + L1(t+1); ONE barrier/step ======
  for (int t = 0; t < T_IN - 1; t++) {
    const int p = t & 1, w = p ^ 1;
    RD_H1A(p) RD_L2M(p) RD_H2P(p)
    MFMA_L2
    ACT2(w, p)                                         // h2(t) + partials(t)
    MFMA_L1
    if (wv == 0 && lane < 2 && t > 0) {                // store y(t-1), off critical path
      float yv_;
      YSUM(p ^ 1, yv_)
      out[(size_t)(b0 + lane) * TT + (t - 1)] = yv_;
    }
    if (tid >= 80 && tid < 82 && t + 2 < T_IN)
      H1X[w][tid - 80][100] = (__fp16)xrow[tid - 80][t + 2];  // x(t+2)
    ACT1_TF(w)                                         // h1(t+1)
    __syncthreads();
  }

  // ---- one-time AR patch: remove x-coefficient from L1 kt3 (x-slot is stale in AR) ----
  if (kg == 0) { W1f[0][3][4] = (__fp16)0.f; W1f[1][3][4] = (__fp16)0.f; }
  if (tid < 16) ((__fp16*)T24)[(3 * 64 + tid) * 8 + 4] = (__fp16)0.f;  // slot3 kg0 elem k=100
  __syncthreads();  // patch visible to wave10 before first AR MFMA_L1

  // ====== autoregressive: 2 barriers/step; y via per-wave partial reduce ======
  for (int t = T_IN - 1; t < TT; t++) {
    const int p = t & 1, w = p ^ 1;
    RD_H1A(p) RD_L2M(p) RD_H2P(p)
    MFMA_L2                                            // gates2(t)
    if (t == T_IN - 1 && wv == 0 && lane < 2) {        // catch-up y(T_IN-2)
      float yv_;
      YSUM(p ^ 1, yv_)
      out[(size_t)(b0 + lane) * TT + (t - 1)] = yv_;
    }
    ACT2(w, p)                                         // h2(t) + partials(t)
    MFMA_L1                                            // L1(t+1) recurrent part (h1(t) only)
    __syncthreads();                                   // B1: h2(t) + partials visible
    float yv;
    YSUM(p, yv)                                        // y(t) = x(t+1), all lanes
    if (wv == 0 && lane < 2) out[(size_t)(b0 + lane) * TT + t] = yv;
    ACT1_AR(w, yv)                                     // h1(t+1), x-term added in-register
    __syncthreads();                                   // B2: h1(t+1) visible
  }
}

extern "C" void kernel_launch(void* const* d_in, const int* in_sizes, int n_in,
                              void* d_out, int out_size, void* d_ws, size_t ws_size,
                              hipStream_t stream) {
  const float* input = (const float*)d_in[0];
  const float* Wih1  = (const float*)d_in[1];
  const float* Whh1  = (const float*)d_in[2];
  const float* bih1  = (const float*)d_in[3];
  const float* bhh1  = (const float*)d_in[4];
  const float* Wih2  = (const float*)d_in[5];
  const float* Whh2  = (const float*)d_in[6];
  const float* bih2  = (const float*)d_in[7];
  const float* bhh2  = (const float*)d_in[8];
  const float* Wlin  = (const float*)d_in[9];
  const float* blin  = (const float*)d_in[10];
  const int*   futp  = (const int*)d_in[11];
  float* out = (float*)d_out;

  dim3 grid(B_TOTAL / NB);  // 256 blocks, 1 per CU
  dim3 block(BLOCK);
  hipLaunchKernelGGL(lstm2_mfma, grid, block, 0, stream,
                     input, Wih1, Whh1, bih1, bhh1, Wih2, Whh2, bih2, bhh2,
                     Wlin, blin, futp, out);
}

// Round 7
// 1444.093 us; speedup vs baseline: 1.5526x; 1.3081x over previous
//
#include <hip/hip_runtime.h>
#include <stdint.h>

// Problem constants
#define HID 100
#define B_TOTAL 512
#define T_IN 1000
#define NB 2
#define BLOCK 512   // 8 waves, 2 waves/SIMD (R4 optimum: TLP vs replication)
#define RSTR 160    // f16 row stride (320 B): batch 1 lands 16 banks away

typedef __fp16 f16x8 __attribute__((ext_vector_type(8)));
typedef __fp16 f16x2 __attribute__((ext_vector_type(2)));
typedef float f32x4 __attribute__((ext_vector_type(4)));

#define MF(A, B, C) __builtin_amdgcn_mfma_f32_16x16x32_f16((A), (B), (C), 0, 0, 0)
#define Z4 ((f32x4){0.f, 0.f, 0.f, 0.f})
#define ZH8 ((f16x8){(__fp16)0.f,(__fp16)0.f,(__fp16)0.f,(__fp16)0.f,(__fp16)0.f,(__fp16)0.f,(__fp16)0.f,(__fp16)0.f})

// ---- fast activation math (verified: absmax unchanged) ----
#if __has_builtin(__builtin_amdgcn_exp2f)
#define EXP2F(x) __builtin_amdgcn_exp2f(x)
#else
#define EXP2F(x) exp2f(x)
#endif
#if __has_builtin(__builtin_amdgcn_rcpf)
#define RCPF(x) __builtin_amdgcn_rcpf(x)
#else
#define RCPF(x) (1.0f / (x))
#endif
#define LOG2E 1.44269504f
__device__ __forceinline__ float sigm(float x) { return RCPF(1.0f + EXP2F(-LOG2E * x)); }
__device__ __forceinline__ float tanh_fast(float x) {
  return 1.0f - 2.0f * RCPF(EXP2F((2.0f * LOG2E) * x) + 1.0f);
}

// 8-wide f16 dot accumulating into f32 (v_dot2_f32_f16 when available)
__device__ __forceinline__ float dot8(f16x8 a, f16x8 b, float acc) {
#if __has_builtin(__builtin_amdgcn_fdot2)
#pragma unroll
  for (int q = 0; q < 4; q++) {
    f16x2 xa = {a[2 * q], a[2 * q + 1]};
    f16x2 xb = {b[2 * q], b[2 * q + 1]};
    acc = __builtin_amdgcn_fdot2(xa, xb, acc, false);
  }
#else
#pragma unroll
  for (int e = 0; e < 8; e++) acc = fmaf((float)a[e], (float)b[e], acc);
#endif
  return acc;
}

// Gate-interleaved row permutation (R1/R2-verified): frag row m of N-tile tl holds
// original gate row g*100 + (4*tl + q), g = m&3, q = m>>2.
// => D: lane holds gates (i,f,g,o) of k=4*tl+(lane>>4), batch lane&1 in regs 0..3.
__device__ __forceinline__ int jmap(int tl, int m) { return (m & 3) * 100 + 4 * tl + (m >> 2); }

// weight element fetchers over padded K layouts (0 in pad regions).
// Bias fused at K=101 (hi) / 102 (lo) against B=1.0 — f32-exact via hi/lo f16 pair.
// L1 K-layout: [0..99]=h1, [100]=x, [101]=b_hi, [102]=b_lo, [103..127]=0
__device__ __forceinline__ __fp16 w1e(const float* Whh1, const float* Wih1,
                                      const float* bih1, const float* bhh1, int j, int k) {
  if (k < 100) return (__fp16)Whh1[j * 100 + k];
  if (k == 100) return (__fp16)Wih1[j];
  if (k == 101 || k == 102) {
    float b = bih1[j] + bhh1[j];
    __fp16 hi = (__fp16)b;
    return (k == 101) ? hi : (__fp16)(b - (float)hi);
  }
  return (__fp16)0.0f;
}
// L2 K-layout: [0..99]=h1(t), [100]=0(x-slot junk), [101]=b_hi, [102]=b_lo,
//              [103..111]=0, [112..211]=h2(t-1), [212..223]=0
__device__ __forceinline__ __fp16 w2e(const float* Wih2, const float* Whh2,
                                      const float* bih2, const float* bhh2, int j, int k) {
  if (k < 100) return (__fp16)Wih2[j * 100 + k];
  if (k == 101 || k == 102) {
    float b = bih2[j] + bhh2[j];
    __fp16 hi = (__fp16)b;
    return (k == 101) ? hi : (__fp16)(b - (float)hi);
  }
  if (k >= 112 && k < 212) return (__fp16)Whh2[j * 100 + (k - 112)];
  return (__fp16)0.0f;
}

// A-operand fragment builders: lane row m=lane&15, K elems (lane>>4)*8+0..7 of K-tile kt
__device__ __forceinline__ f16x8 mka1(const float* Whh1, const float* Wih1,
                                      const float* bih1, const float* bhh1,
                                      int tl, int kt, int m, int kg) {
  int j = jmap(tl, m);
  f16x8 r;
#pragma unroll
  for (int e = 0; e < 8; e++) r[e] = w1e(Whh1, Wih1, bih1, bhh1, j, kt * 32 + kg * 8 + e);
  return r;
}
__device__ __forceinline__ f16x8 mka2(const float* Wih2, const float* Whh2,
                                      const float* bih2, const float* bhh2,
                                      int tl, int kt, int m, int kg) {
  int j = jmap(tl, m);
  f16x8 r;
#pragma unroll
  for (int e = 0; e < 8; e++) r[e] = w2e(Wih2, Whh2, bih2, bhh2, j, kt * 32 + kg * 8 + e);
  return r;
}

__global__ __launch_bounds__(BLOCK, 2) void lstm2_mfma(
    const float* __restrict__ input,  // [512,1000]
    const float* __restrict__ Wih1,   // [400,1]
    const float* __restrict__ Whh1,   // [400,100]
    const float* __restrict__ bih1,
    const float* __restrict__ bhh1,
    const float* __restrict__ Wih2,   // [400,100]
    const float* __restrict__ Whh2,   // [400,100]
    const float* __restrict__ bih2,
    const float* __restrict__ bhh2,
    const float* __restrict__ Wlin,   // [1,100]
    const float* __restrict__ blin,   // [1]
    const int* __restrict__ futp,
    float* __restrict__ out)          // [512, 1000+future]
{
  // parity double-buffered activation vectors (B-operand sources)
  __shared__ __align__(16) __fp16 H1X[2][NB][RSTR];  // h1 | x@100 | 1.0@101,102 | 0
  __shared__ __align__(16) __fp16 H2s[2][NB][RSTR];  // h2 | 0 pads
  __shared__ __align__(16) float  xrow[NB][T_IN];    // staged inputs (8 KB)

  const int tid = threadIdx.x;
  const int lane = tid & 63;
  const int wv = tid >> 6;
  const int b0 = blockIdx.x * NB;
  const int F = futp[0];
  const int TT = T_IN + F;

  // ---------------- init: stage + zero ----------------
  for (int i = tid; i < NB * T_IN; i += BLOCK) {
    int b = i / T_IN, tt = i % T_IN;
    xrow[b][tt] = input[(size_t)(b0 + b) * T_IN + tt];
  }
  if (tid < 320) { ((uint32_t*)H1X)[tid] = 0u; ((uint32_t*)H2s)[tid] = 0u; }

  const int n15 = lane & 15;
  const int kg = lane >> 4;         // K-chunk index 0..3
  const int bcol = lane & 1;        // batch for B-reads

  // ---- act geometry: lane activates ONE of its accumulator quads ----
  const int sel = lane & 15;
  const int cg  = sel >> 1;                       // col-group
  const int ab  = sel & 1;                        // batch
  const int aq  = lane >> 4;                      // q 0..3
  const int atl = (cg == 0) ? wv : (cg == 1) ? 8 + wv : (cg == 2) ? 16 + wv : 24;
  const int ak  = atl * 4 + aq;                   // k index this lane owns (0..99)
  const bool awr1 = (sel < 6) || (wv == 0 && sel < 8);   // L1 writers (wave0 owns tile 24)
  const bool awr2 = (sel < 6) || (wv == 1 && sel < 8);   // L2 writers (wave1 owns tile 24)
  float c1v = 0.0f, c2v = 0.0f;                   // per-lane cell states
  const float blin0 = blin[0];

  // ---- y/AR-fold constants: Wlin chunks (per-lane) + Wih1 gate-quad (per-lane) ----
  f16x8 wlinv[4];
#pragma unroll
  for (int i = 0; i < 4; i++) {
#pragma unroll
    for (int e = 0; e < 8; e++) {
      int k = i * 32 + kg * 8 + e;
      wlinv[i][e] = (__fp16)((k < HID) ? Wlin[k] : 0.f);
    }
  }
  f32x4 wih1q;
#pragma unroll
  for (int g = 0; g < 4; g++) wih1q[g] = Wih1[g * 100 + ak];

  // ---- register-resident weight fragments (A-operand), tiles {wv, 8+wv, 16+wv} ----
  f16x8 W1f0[4], W1f1[4], W1f2[4], W2f0[7], W2f1[7], W2f2[7];
#pragma unroll
  for (int kt = 0; kt < 4; kt++) {
    W1f0[kt] = mka1(Whh1, Wih1, bih1, bhh1, wv, kt, n15, kg);
    W1f1[kt] = mka1(Whh1, Wih1, bih1, bhh1, 8 + wv, kt, n15, kg);
    W1f2[kt] = mka1(Whh1, Wih1, bih1, bhh1, 16 + wv, kt, n15, kg);
  }
#pragma unroll
  for (int kt = 0; kt < 7; kt++) {
    W2f0[kt] = mka2(Wih2, Whh2, bih2, bhh2, wv, kt, n15, kg);
    W2f1[kt] = mka2(Wih2, Whh2, bih2, bhh2, 8 + wv, kt, n15, kg);
    W2f2[kt] = mka2(Wih2, Whh2, bih2, bhh2, 16 + wv, kt, n15, kg);
  }
  // tile-24 fragments in REGISTERS: L1-half on wave 0, L2-half on wave 1 (no LDS re-reads)
  f16x8 W1T[4], W2T[7];
#pragma unroll
  for (int kt = 0; kt < 4; kt++) W1T[kt] = ZH8;
#pragma unroll
  for (int kt = 0; kt < 7; kt++) W2T[kt] = ZH8;
  if (wv == 0) {
#pragma unroll
    for (int kt = 0; kt < 4; kt++) W1T[kt] = mka1(Whh1, Wih1, bih1, bhh1, 24, kt, n15, kg);
  }
  if (wv == 1) {
#pragma unroll
    for (int kt = 0; kt < 7; kt++) W2T[kt] = mka2(Wih2, Whh2, bih2, bhh2, 24, kt, n15, kg);
  }

  __syncthreads();
  // specials: bias-ones at K=101,102 (both parities/batches); x(0) into parity 1
  if (tid < 4) { H1X[tid >> 1][tid & 1][101] = (__fp16)1.0f; H1X[tid >> 1][tid & 1][102] = (__fp16)1.0f; }
  if (tid >= 4 && tid < 6) H1X[1][tid - 4][100] = (__fp16)xrow[tid - 4][0];
  __syncthreads();

  f16x8 bH1a[4], bH2[3], bl2m;
  f32x4 c0, c1, c2, d0, d1, d2;
  f32x4 c3 = Z4, d3 = Z4;           // tile-24 accs (live only on waves 0/1)
  const f32x4 zz = Z4;              // persistent zero C-operand (kills per-step acc-init movs)

// ---- B-operand reads (L1 and L2 share H1X kts 0..3) ----
#define RD_H1A(P) { _Pragma("unroll") for (int kt_ = 0; kt_ < 4; kt_++) \
    bH1a[kt_] = *(const f16x8*)&H1X[P][bcol][kt_ * 32 + kg * 8]; }
#define RD_L2M(P) { f16x8 hm_ = *(const f16x8*)&H2s[P][bcol][(kg >= 2) ? ((kg - 2) * 8) : 0]; \
    bl2m = (kg >= 2) ? hm_ : bH1a[3]; }
#define RD_H2P(P) { _Pragma("unroll") for (int kt_ = 0; kt_ < 3; kt_++) \
    bH2[kt_] = *(const f16x8*)&H2s[P][bcol][16 + kt_ * 32 + kg * 8]; }

// ---- MFMA bursts (bias arrives via K=101/102; first MFMA uses zz as C) ----
#define MFMA_L2 { \
    d0 = MF(W2f0[0], bH1a[0], zz); d1 = MF(W2f1[0], bH1a[0], zz); d2 = MF(W2f2[0], bH1a[0], zz); \
    d0 = MF(W2f0[1], bH1a[1], d0); d1 = MF(W2f1[1], bH1a[1], d1); d2 = MF(W2f2[1], bH1a[1], d2); \
    d0 = MF(W2f0[2], bH1a[2], d0); d1 = MF(W2f1[2], bH1a[2], d1); d2 = MF(W2f2[2], bH1a[2], d2); \
    d0 = MF(W2f0[3], bl2m, d0);    d1 = MF(W2f1[3], bl2m, d1);    d2 = MF(W2f2[3], bl2m, d2); \
    d0 = MF(W2f0[4], bH2[0], d0);  d1 = MF(W2f1[4], bH2[0], d1);  d2 = MF(W2f2[4], bH2[0], d2); \
    d0 = MF(W2f0[5], bH2[1], d0);  d1 = MF(W2f1[5], bH2[1], d1);  d2 = MF(W2f2[5], bH2[1], d2); \
    d0 = MF(W2f0[6], bH2[2], d0);  d1 = MF(W2f1[6], bH2[2], d1);  d2 = MF(W2f2[6], bH2[2], d2); \
    if (wv == 1) { \
      d3 = MF(W2T[0], bH1a[0], zz); d3 = MF(W2T[1], bH1a[1], d3); d3 = MF(W2T[2], bH1a[2], d3); \
      d3 = MF(W2T[3], bl2m, d3); \
      d3 = MF(W2T[4], bH2[0], d3);  d3 = MF(W2T[5], bH2[1], d3);  d3 = MF(W2T[6], bH2[2], d3); } }

#define MFMA_L1 { \
    c0 = MF(W1f0[0], bH1a[0], zz); c1 = MF(W1f1[0], bH1a[0], zz); c2 = MF(W1f2[0], bH1a[0], zz); \
    c0 = MF(W1f0[1], bH1a[1], c0); c1 = MF(W1f1[1], bH1a[1], c1); c2 = MF(W1f2[1], bH1a[1], c2); \
    c0 = MF(W1f0[2], bH1a[2], c0); c1 = MF(W1f1[2], bH1a[2], c1); c2 = MF(W1f2[2], bH1a[2], c2); \
    c0 = MF(W1f0[3], bH1a[3], c0); c1 = MF(W1f1[3], bH1a[3], c1); c2 = MF(W1f2[3], bH1a[3], c2); \
    if (wv == 0) { \
      c3 = MF(W1T[0], bH1a[0], zz); c3 = MF(W1T[1], bH1a[1], c3); \
      c3 = MF(W1T[2], bH1a[2], c3); c3 = MF(W1T[3], bH1a[3], c3); } }

// ---- in-register activations ----
#define ACT1_TF(W_) { \
    f32x4 qq = (cg == 0) ? c0 : (cg == 1) ? c1 : (cg == 2) ? c2 : c3; \
    float sf_ = sigm(qq[1]), si_ = sigm(qq[0]), tg_ = tanh_fast(qq[2]); \
    c1v = sf_ * c1v + si_ * tg_; \
    float h_ = sigm(qq[3]) * tanh_fast(c1v); \
    if (awr1) H1X[W_][ab][ak] = (__fp16)h_; }

#define ACT1_AR(W_, YV_) { \
    f32x4 qq = (cg == 0) ? c0 : (cg == 1) ? c1 : (cg == 2) ? c2 : c3; \
    qq[0] = fmaf(wih1q[0], (YV_), qq[0]); qq[1] = fmaf(wih1q[1], (YV_), qq[1]); \
    qq[2] = fmaf(wih1q[2], (YV_), qq[2]); qq[3] = fmaf(wih1q[3], (YV_), qq[3]); \
    float sf_ = sigm(qq[1]), si_ = sigm(qq[0]), tg_ = tanh_fast(qq[2]); \
    c1v = sf_ * c1v + si_ * tg_; \
    float h_ = sigm(qq[3]) * tanh_fast(c1v); \
    if (awr1) H1X[W_][ab][ak] = (__fp16)h_; }

#define ACT2(W_) { \
    f32x4 qq = (cg == 0) ? d0 : (cg == 1) ? d1 : (cg == 2) ? d2 : d3; \
    float sf_ = sigm(qq[1]), si_ = sigm(qq[0]), tg_ = tanh_fast(qq[2]); \
    c2v = sf_ * c2v + si_ * tg_; \
    float h_ = sigm(qq[3]) * tanh_fast(c2v); \
    if (awr2) H2s[W_][ab][ak] = (__fp16)h_; }

// TF y-output: wave 7 only — dot8 over f16 h2 (same math as AR fold), 4 reads + 2 shfl
#define YTF(tt, P_) { if (wv == 7) { \
    float s_ = 0.0f; \
    _Pragma("unroll") for (int i_ = 0; i_ < 4; i_++) { \
      f16x8 hh_ = *(const f16x8*)&H2s[P_][bcol][i_ * 32 + kg * 8]; \
      s_ = dot8(hh_, wlinv[i_], s_); } \
    s_ += __shfl_xor(s_, 16, 64); \
    s_ += __shfl_xor(s_, 32, 64); \
    if (lane < 2) out[(size_t)(b0 + lane) * TT + (tt)] = s_ + blin0; } }

  // ---------------- prologue: L1 gates(0) from parity 1 (zeros + x(0)) ----------------
  RD_H1A(1)
  MFMA_L1
  ACT1_TF(0)                                           // h1(0) -> H1X[0]
  if (tid >= 384 && tid < 386) H1X[0][tid - 384][100] = (__fp16)xrow[tid - 384][1];  // x(1)
  __syncthreads();

  // ====== teacher-forced fused: iter t does L2(t) + L1(t+1); ONE barrier/step ======
  for (int t = 0; t < T_IN - 1; t++) {
    const int p = t & 1, w = p ^ 1;
    RD_H1A(p) RD_L2M(p) RD_H2P(p)
    MFMA_L2
    ACT2(w)                                            // h2(t)
    MFMA_L1
    if (t > 0) YTF(t - 1, p)                           // y(t-1) from h2(t-1), off critical path
    if (tid >= 384 && tid < 386 && t + 2 < T_IN)
      H1X[w][tid - 384][100] = (__fp16)xrow[tid - 384][t + 2];  // x(t+2)
    ACT1_TF(w)                                         // h1(t+1)
    __syncthreads();
  }

  // ---- one-time AR patch: remove x-coefficient from L1 kt3 (x-slot is stale in AR) ----
  // all patches are per-wave registers -> no barrier needed
  if (kg == 0) {
    W1f0[3][4] = (__fp16)0.f; W1f1[3][4] = (__fp16)0.f; W1f2[3][4] = (__fp16)0.f;
    if (wv == 0) W1T[3][4] = (__fp16)0.f;
  }

  // ====== autoregressive: 2 barriers/step; y folded as rank-1 scalar (s = Wlin.h2) ======
  for (int t = T_IN - 1; t < TT; t++) {
    const int p = t & 1, w = p ^ 1;
    RD_H1A(p) RD_L2M(p) RD_H2P(p)
    MFMA_L2                                            // gates2(t)
    if (t == T_IN - 1) YTF(t - 1, p)                   // catch-up y(T_IN-2)
    ACT2(w)                                            // h2(t)
    MFMA_L1                                            // L1(t+1) recurrent part (h1(t) only)
    __syncthreads();                                   // B1: h2(t) visible
    float s_ = 0.f;
#pragma unroll
    for (int i_ = 0; i_ < 4; i_++) {                   // s = Wlin . h2(t)  (per-lane batch)
      f16x8 hh_ = *(const f16x8*)&H2s[w][bcol][i_ * 32 + kg * 8];
      s_ = dot8(hh_, wlinv[i_], s_);
    }
    s_ += __shfl_xor(s_, 16, 64);
    s_ += __shfl_xor(s_, 32, 64);
    const float yv = s_ + blin0;                       // y(t) = x(t+1)
    if (wv == 0 && lane < 2) out[(size_t)(b0 + lane) * TT + t] = yv;
    ACT1_AR(w, yv)                                     // h1(t+1), x-term added in-register
    __syncthreads();                                   // B2: h1(t+1) visible
  }
}

extern "C" void kernel_launch(void* const* d_in, const int* in_sizes, int n_in,
                              void* d_out, int out_size, void* d_ws, size_t ws_size,
                              hipStream_t stream) {
  const float* input = (const float*)d_in[0];
  const float* Wih1  = (const float*)d_in[1];
  const float* Whh1  = (const float*)d_in[2];
  const float* bih1  = (const float*)d_in[3];
  const float* bhh1  = (const float*)d_in[4];
  const float* Wih2  = (const float*)d_in[5];
  const float* Whh2  = (const float*)d_in[6];
  const float* bih2  = (const float*)d_in[7];
  const float* bhh2  = (const float*)d_in[8];
  const float* Wlin  = (const float*)d_in[9];
  const float* blin  = (const float*)d_in[10];
  const int*   futp  = (const int*)d_in[11];
  float* out = (float*)d_out;

  dim3 grid(B_TOTAL / NB);  // 256 blocks, 1 per CU
  dim3 block(BLOCK);
  hipLaunchKernelGGL(lstm2_mfma, grid, block, 0, stream,
                     input, Wih1, Whh1, bih1, bhh1, Wih2, Whh2, bih2, bhh2,
                     Wlin, blin, futp, out);
}